// Round 1
// baseline (3103.806 us; speedup 1.0000x reference)
//
#include <hip/hip_runtime.h>

using f32x4  = __attribute__((ext_vector_type(4))) float;
using short8 = __attribute__((ext_vector_type(8))) short;
using ushort4_t = __attribute__((ext_vector_type(4))) unsigned short;

#define XP 136  // padded LDS pitch in bf16 elems (272B rows: 16B-aligned, 2-way-free banks)

static __device__ __forceinline__ unsigned short f2bf(float f) {
  union { float f; unsigned u; } c; c.f = f;
  unsigned u = c.u;
  return (unsigned short)((u + 0x7fffu + ((u >> 16) & 1u)) >> 16);  // RNE
}

// edge_index may arrive as int64 (reference dtype) or int32 (harness downcast).
static __device__ __forceinline__ int load_idx(const void* ei, int is64, long long pos) {
  if (is64) return (int)((const long long*)ei)[pos];
  return ((const int*)ei)[pos];
}

__global__ __launch_bounds__(64) void k_detect(const void* ei, int nnodes, int* flag) {
  if (threadIdx.x != 0) return;
  const long long* e64 = (const long long*)ei;
  int ok = 1;
  for (int i = 0; i < 64; ++i) {
    long long v = e64[i];
    if (v < 0 || v >= (long long)nnodes) { ok = 0; break; }
  }
  *flag = ok;
}

// K1: h[n][col] = sum_i x[n][i] * Wflat[i][col], col = head*32+o.
// bf16 MFMA 16x16x32, f32 accum. Block = 256 thr (4 waves) x 64 rows.
__global__ __launch_bounds__(256) void k_gemm(const float* __restrict__ x,
                                              const float* __restrict__ W,
                                              float* __restrict__ h, int nnodes) {
  __shared__ __align__(16) unsigned short lx[64 * XP];   // x tile [row][k]
  __shared__ __align__(16) unsigned short lw[128 * XP];  // W^T   [col][k]
  const int tid = threadIdx.x;
  const int n0 = blockIdx.x * 64;

  // stage x: 64 rows x 128 cols as float4 (2048 float4s, 8/thread)
  for (int it = 0; it < 8; ++it) {
    int idx = tid + it * 256;       // float4 index
    int r = idx >> 5, i4 = idx & 31;
    int n = n0 + r;
    float4 v = make_float4(0.f, 0.f, 0.f, 0.f);
    if (n < nnodes) v = *(const float4*)(x + (size_t)n * 128 + i4 * 4);
    ushort4_t b; b.x = f2bf(v.x); b.y = f2bf(v.y); b.z = f2bf(v.z); b.w = f2bf(v.w);
    *(ushort4_t*)&lx[r * XP + i4 * 4] = b;
  }
  // stage W^T: W global layout [head][i][o] linear = head*4096 + i*32 + o
  for (int it = 0; it < 64; ++it) {
    int idx = tid + it * 256;               // coalesced global read
    int hh = idx >> 12, i = (idx >> 5) & 127, o = idx & 31;
    int col = hh * 32 + o;
    lw[col * XP + i] = f2bf(W[idx]);
  }
  __syncthreads();

  const int wave = tid >> 6, lane = tid & 63;
  const int m0 = wave * 16;
  const int lr = lane & 15, lh = lane >> 4;

  f32x4 acc[8] = {};
  for (int kk = 0; kk < 4; ++kk) {
    short8 a = *(const short8*)&lx[(m0 + lr) * XP + kk * 32 + lh * 8];
#pragma unroll
    for (int f = 0; f < 8; ++f) {
      short8 b = *(const short8*)&lw[(f * 16 + lr) * XP + kk * 32 + lh * 8];
      acc[f] = __builtin_amdgcn_mfma_f32_16x16x32_bf16(a, b, acc[f], 0, 0, 0);
    }
  }
  // D layout: row = lh*4 + j, col = lr
#pragma unroll
  for (int f = 0; f < 8; ++f) {
#pragma unroll
    for (int j = 0; j < 4; ++j) {
      int n = n0 + m0 + lh * 4 + j;
      if (n < nnodes) h[(size_t)n * 128 + f * 16 + lr] = acc[f][j];
    }
  }
}

// K1b: per-node attention scalars s_src/s_dst [N][4]
__global__ __launch_bounds__(256) void k_s(const float* __restrict__ h,
                                           const float* __restrict__ a,
                                           float* __restrict__ ssrc,
                                           float* __restrict__ sdst, int nnodes) {
  int gid = blockIdx.x * 256 + threadIdx.x;
  if (gid >= nnodes * 4) return;
  int n = gid >> 2, hh = gid & 3;
  const float* hp = h + (size_t)n * 128 + hh * 32;
  const float* ap = a + hh * 64;
  float s0 = 0.f, s1 = 0.f;
#pragma unroll
  for (int o = 0; o < 32; ++o) {
    float v = hp[o];
    s0 += v * ap[o];
    s1 += v * ap[32 + o];
  }
  ssrc[gid] = s0;
  sdst[gid] = s1;
}

// K2: per-edge logits -> p = exp(leaky_relu(e)); seg_sum[dst] += p
__global__ __launch_bounds__(256) void k_edge(const void* __restrict__ ei, const int* __restrict__ flag,
                                              const float* __restrict__ ssrc,
                                              const float* __restrict__ sdst,
                                              float* __restrict__ pbuf,
                                              float* __restrict__ segsum, int E) {
  int e = blockIdx.x * 256 + threadIdx.x;
  if (e >= E) return;
  int is64 = *flag;
  int src = load_idx(ei, is64, e);
  int dst = load_idx(ei, is64, (long long)E + e);
  float4 ss = *(const float4*)(ssrc + (size_t)src * 4);
  float4 sd = *(const float4*)(sdst + (size_t)dst * 4);
  float4 p;
  float v;
  v = ss.x + sd.x; v = v > 0.f ? v : 0.2f * v; p.x = __expf(v);
  v = ss.y + sd.y; v = v > 0.f ? v : 0.2f * v; p.y = __expf(v);
  v = ss.z + sd.z; v = v > 0.f ? v : 0.2f * v; p.z = __expf(v);
  v = ss.w + sd.w; v = v > 0.f ? v : 0.2f * v; p.w = __expf(v);
  *(float4*)(pbuf + (size_t)e * 4) = p;
  atomicAdd(&segsum[(size_t)dst * 4 + 0], p.x);
  atomicAdd(&segsum[(size_t)dst * 4 + 1], p.y);
  atomicAdd(&segsum[(size_t)dst * 4 + 2], p.z);
  atomicAdd(&segsum[(size_t)dst * 4 + 3], p.w);
}

// K3: out[dst] += p * h[src]  (unnormalized; one thread per (edge, 4-col quad))
__global__ __launch_bounds__(256) void k_msg(const void* __restrict__ ei, const int* __restrict__ flag,
                                             const float* __restrict__ h,
                                             const float* __restrict__ pbuf,
                                             float* __restrict__ out, int E) {
  int id = blockIdx.x * 256 + threadIdx.x;
  int e = id >> 5, q = id & 31;       // q: which float4 of the 128 cols
  if (e >= E) return;
  int is64 = *flag;
  int src = load_idx(ei, is64, e);
  int dst = load_idx(ei, is64, (long long)E + e);
  float p = pbuf[(size_t)e * 4 + (q >> 3)];   // head = (q*4)>>5
  float4 hv = *(const float4*)(h + (size_t)src * 128 + q * 4);
  float* op = out + (size_t)dst * 128 + q * 4;
  atomicAdd(op + 0, p * hv.x);
  atomicAdd(op + 1, p * hv.y);
  atomicAdd(op + 2, p * hv.z);
  atomicAdd(op + 3, p * hv.w);
}

// K4: normalize by seg_sum (0 for empty segments)
__global__ __launch_bounds__(256) void k_norm(float* __restrict__ out,
                                              const float* __restrict__ segsum, int nnodes) {
  int gid = blockIdx.x * 256 + threadIdx.x;
  if (gid >= nnodes * 128) return;
  int n = gid >> 7, c = gid & 127;
  float s = segsum[(size_t)n * 4 + (c >> 5)];
  float v = out[gid];
  out[gid] = (s > 0.f) ? v / s : 0.f;
}

extern "C" void kernel_launch(void* const* d_in, const int* in_sizes, int n_in,
                              void* d_out, int out_size, void* d_ws, size_t ws_size,
                              hipStream_t stream) {
  const float* x = (const float*)d_in[0];
  const void*  ei = d_in[1];
  const float* W = (const float*)d_in[2];
  const float* a = (const float*)d_in[3];
  float* out = (float*)d_out;

  const int N = in_sizes[0] / 128;
  const int E = in_sizes[1] / 2;

  float* ws = (float*)d_ws;
  float* h      = ws;                          // N*128
  float* ssrc   = h + (size_t)N * 128;         // N*4
  float* sdst   = ssrc + (size_t)N * 4;        // N*4
  float* pbuf   = sdst + (size_t)N * 4;        // E*4
  float* segsum = pbuf + (size_t)E * 4;        // N*4
  int*   flag   = (int*)(segsum + (size_t)N * 4);

  hipMemsetAsync(out, 0, (size_t)out_size * sizeof(float), stream);
  hipMemsetAsync(segsum, 0, (size_t)N * 4 * sizeof(float), stream);

  k_detect<<<1, 64, 0, stream>>>(ei, N, flag);
  k_gemm<<<(N + 63) / 64, 256, 0, stream>>>(x, W, h, N);
  k_s<<<(N * 4 + 255) / 256, 256, 0, stream>>>(h, a, ssrc, sdst, N);
  k_edge<<<(E + 255) / 256, 256, 0, stream>>>(ei, flag, ssrc, sdst, pbuf, segsum, E);
  k_msg<<<(int)(((long long)E * 32 + 255) / 256), 256, 0, stream>>>(ei, flag, h, pbuf, out, E);
  k_norm<<<(N * 128 + 255) / 256, 256, 0, stream>>>(out, segsum, N);
}

// Round 2
// 448.265 us; speedup vs baseline: 6.9240x; 6.9240x over previous
//
#include <hip/hip_runtime.h>

using f32x4  = __attribute__((ext_vector_type(4))) float;
using short8 = __attribute__((ext_vector_type(8))) short;
using ushort4_t = __attribute__((ext_vector_type(4))) unsigned short;

#define XP 136  // padded LDS pitch in bf16 elems

static __device__ __forceinline__ unsigned short f2bf(float f) {
  union { float f; unsigned u; } c; c.f = f;
  unsigned u = c.u;
  return (unsigned short)((u + 0x7fffu + ((u >> 16) & 1u)) >> 16);  // RNE
}

// edge_index may arrive as int64 (reference dtype) or int32 (harness downcast).
static __device__ __forceinline__ int load_idx(const void* ei, int is64, long long pos) {
  if (is64) return (int)((const long long*)ei)[pos];
  return ((const int*)ei)[pos];
}

__global__ __launch_bounds__(64) void k_detect(const void* ei, int nnodes, int* flag) {
  if (threadIdx.x != 0) return;
  const long long* e64 = (const long long*)ei;
  int ok = 1;
  for (int i = 0; i < 64; ++i) {
    long long v = e64[i];
    if (v < 0 || v >= (long long)nnodes) { ok = 0; break; }
  }
  *flag = ok;
}

// K1: h = x @ W  (bf16 MFMA, f32 accum). Block = 256 thr x 64 rows.
__global__ __launch_bounds__(256) void k_gemm(const float* __restrict__ x,
                                              const float* __restrict__ W,
                                              float* __restrict__ h, int nnodes) {
  __shared__ __align__(16) unsigned short lx[64 * XP];
  __shared__ __align__(16) unsigned short lw[128 * XP];
  const int tid = threadIdx.x;
  const int n0 = blockIdx.x * 64;

  for (int it = 0; it < 8; ++it) {
    int idx = tid + it * 256;
    int r = idx >> 5, i4 = idx & 31;
    int n = n0 + r;
    float4 v = make_float4(0.f, 0.f, 0.f, 0.f);
    if (n < nnodes) v = *(const float4*)(x + (size_t)n * 128 + i4 * 4);
    ushort4_t b; b.x = f2bf(v.x); b.y = f2bf(v.y); b.z = f2bf(v.z); b.w = f2bf(v.w);
    *(ushort4_t*)&lx[r * XP + i4 * 4] = b;
  }
  for (int it = 0; it < 64; ++it) {
    int idx = tid + it * 256;
    int hh = idx >> 12, i = (idx >> 5) & 127, o = idx & 31;
    int col = hh * 32 + o;
    lw[col * XP + i] = f2bf(W[idx]);
  }
  __syncthreads();

  const int wave = tid >> 6, lane = tid & 63;
  const int m0 = wave * 16;
  const int lr = lane & 15, lh = lane >> 4;

  f32x4 acc[8] = {};
  for (int kk = 0; kk < 4; ++kk) {
    short8 a = *(const short8*)&lx[(m0 + lr) * XP + kk * 32 + lh * 8];
#pragma unroll
    for (int f = 0; f < 8; ++f) {
      short8 b = *(const short8*)&lw[(f * 16 + lr) * XP + kk * 32 + lh * 8];
      acc[f] = __builtin_amdgcn_mfma_f32_16x16x32_bf16(a, b, acc[f], 0, 0, 0);
    }
  }
#pragma unroll
  for (int f = 0; f < 8; ++f) {
#pragma unroll
    for (int j = 0; j < 4; ++j) {
      int n = n0 + m0 + lh * 4 + j;
      if (n < nnodes) h[(size_t)n * 128 + f * 16 + lr] = acc[f][j];
    }
  }
}

// K1b: per-node attention scalars s_src/s_dst [N][4]
__global__ __launch_bounds__(256) void k_s(const float* __restrict__ h,
                                           const float* __restrict__ a,
                                           float* __restrict__ ssrc,
                                           float* __restrict__ sdst, int nnodes) {
  int gid = blockIdx.x * 256 + threadIdx.x;
  if (gid >= nnodes * 4) return;
  int n = gid >> 2, hh = gid & 3;
  const float* hp = h + (size_t)n * 128 + hh * 32;
  const float* ap = a + hh * 64;
  float s0 = 0.f, s1 = 0.f;
#pragma unroll
  for (int o = 0; o < 32; ++o) {
    float v = hp[o];
    s0 += v * ap[o];
    s1 += v * ap[32 + o];
  }
  ssrc[gid] = s0;
  sdst[gid] = s1;
}

// ---- CSR build ----
__global__ __launch_bounds__(256) void k_deg(const void* __restrict__ ei, const int* __restrict__ flag,
                                             int* __restrict__ deg, int E) {
  int e = blockIdx.x * 256 + threadIdx.x;
  if (e >= E) return;
  int dst = load_idx(ei, *flag, (long long)E + e);
  atomicAdd(&deg[dst], 1);
}

__global__ __launch_bounds__(256) void k_scan1(const int* __restrict__ deg, int* __restrict__ rowstart,
                                               int* __restrict__ bsum, int N) {
  __shared__ int l[256];
  int t = threadIdx.x;
  int gid = blockIdx.x * 256 + t;
  int v = (gid < N) ? deg[gid] : 0;
  l[t] = v;
  __syncthreads();
  for (int off = 1; off < 256; off <<= 1) {
    int u = (t >= off) ? l[t - off] : 0;
    __syncthreads();
    l[t] += u;
    __syncthreads();
  }
  if (gid < N) rowstart[gid] = l[t] - v;       // exclusive within block
  if (t == 255) bsum[blockIdx.x] = l[255];
}

__global__ __launch_bounds__(512) void k_scan2(int* __restrict__ bsum, int nb) {
  __shared__ int l[512];
  int t = threadIdx.x;
  int v = (t < nb) ? bsum[t] : 0;
  l[t] = v;
  __syncthreads();
  for (int off = 1; off < 512; off <<= 1) {
    int u = (t >= off) ? l[t - off] : 0;
    __syncthreads();
    l[t] += u;
    __syncthreads();
  }
  if (t < nb) bsum[t] = l[t] - v;              // exclusive
}

__global__ __launch_bounds__(256) void k_scan3(int* __restrict__ rowstart, const int* __restrict__ bsum,
                                               int* __restrict__ cursor, int N) {
  int gid = blockIdx.x * 256 + threadIdx.x;
  if (gid < N) {
    int r = rowstart[gid] + bsum[blockIdx.x];
    rowstart[gid] = r;
    cursor[gid] = r;
  }
}

__global__ __launch_bounds__(256) void k_scatter(const void* __restrict__ ei, const int* __restrict__ flag,
                                                 int* __restrict__ cursor, int* __restrict__ eidx, int E) {
  int e = blockIdx.x * 256 + threadIdx.x;
  if (e >= E) return;
  int is64 = *flag;
  int src = load_idx(ei, is64, e);
  int dst = load_idx(ei, is64, (long long)E + e);
  int pos = atomicAdd(&cursor[dst], 1);
  eidx[pos] = src;
}

// ---- gather: one wave per dst node; softmax + weighted sum fused ----
__global__ __launch_bounds__(256) void k_gather(const float* __restrict__ h,
                                                const float* __restrict__ ssrc,
                                                const float* __restrict__ sdst,
                                                const int* __restrict__ rowstart,
                                                const int* __restrict__ deg,
                                                const int* __restrict__ eidx,
                                                float* __restrict__ out, int N) {
  int wid = (blockIdx.x * 256 + threadIdx.x) >> 6;
  int lane = threadIdx.x & 63;
  if (wid >= N) return;
  const int dst = wid;
  const int beg = rowstart[dst];
  const int end = beg + deg[dst];
  const int h0 = lane >> 5;                    // head for col = lane (0/1)
  const float sd0 = sdst[(size_t)dst * 4 + h0];
  const float sd1 = sdst[(size_t)dst * 4 + 2 + h0];
  float acc0 = 0.f, acc1 = 0.f, ps0 = 0.f, ps1 = 0.f;
  for (int i = beg; i < end; ++i) {
    int src = eidx[i];
    const float* hp = h + (size_t)src * 128;
    float hv0 = hp[lane];
    float hv1 = hp[64 + lane];
    float s0 = ssrc[(size_t)src * 4 + h0] + sd0;
    float s1 = ssrc[(size_t)src * 4 + 2 + h0] + sd1;
    s0 = s0 > 0.f ? s0 : 0.2f * s0;
    s1 = s1 > 0.f ? s1 : 0.2f * s1;
    float p0 = __expf(s0), p1 = __expf(s1);
    acc0 += p0 * hv0;  ps0 += p0;
    acc1 += p1 * hv1;  ps1 += p1;
  }
  out[(size_t)dst * 128 + lane]      = ps0 > 0.f ? acc0 / ps0 : 0.f;
  out[(size_t)dst * 128 + 64 + lane] = ps1 > 0.f ? acc1 / ps1 : 0.f;
}

extern "C" void kernel_launch(void* const* d_in, const int* in_sizes, int n_in,
                              void* d_out, int out_size, void* d_ws, size_t ws_size,
                              hipStream_t stream) {
  const float* x = (const float*)d_in[0];
  const void*  ei = d_in[1];
  const float* W = (const float*)d_in[2];
  const float* a = (const float*)d_in[3];
  float* out = (float*)d_out;

  const int N = in_sizes[0] / 128;
  const int E = in_sizes[1] / 2;
  const int NB = (N + 255) / 256;              // scan blocks (<=512)

  char* ws = (char*)d_ws;
  float* h        = (float*)ws;                          ws += (size_t)N * 128 * 4;
  float* ssrc     = (float*)ws;                          ws += (size_t)N * 4 * 4;
  float* sdst     = (float*)ws;                          ws += (size_t)N * 4 * 4;
  int*   deg      = (int*)ws;                            ws += (size_t)N * 4;
  int*   rowstart = (int*)ws;                            ws += (size_t)N * 4;
  int*   cursor   = (int*)ws;                            ws += (size_t)N * 4;
  int*   bsum     = (int*)ws;                            ws += 512 * 4;
  int*   eidx     = (int*)ws;                            ws += (size_t)E * 4;
  int*   flag     = (int*)ws;

  hipMemsetAsync(deg, 0, (size_t)N * 4, stream);

  k_detect<<<1, 64, 0, stream>>>(ei, N, flag);
  k_gemm<<<(N + 63) / 64, 256, 0, stream>>>(x, W, h, N);
  k_s<<<(N * 4 + 255) / 256, 256, 0, stream>>>(h, a, ssrc, sdst, N);
  k_deg<<<(E + 255) / 256, 256, 0, stream>>>(ei, flag, deg, E);
  k_scan1<<<NB, 256, 0, stream>>>(deg, rowstart, bsum, N);
  k_scan2<<<1, 512, 0, stream>>>(bsum, NB);
  k_scan3<<<NB, 256, 0, stream>>>(rowstart, bsum, cursor, N);
  k_scatter<<<(E + 255) / 256, 256, 0, stream>>>(ei, flag, cursor, eidx, E);
  k_gather<<<(N + 3) / 4, 256, 0, stream>>>(h, ssrc, sdst, rowstart, deg, eidx, out, N);
}

// Round 3
// 343.244 us; speedup vs baseline: 9.0426x; 1.3060x over previous
//
#include <hip/hip_runtime.h>

using f32x4  = __attribute__((ext_vector_type(4))) float;
using short8 = __attribute__((ext_vector_type(8))) short;
using ushort4_t = __attribute__((ext_vector_type(4))) unsigned short;

#define XP 136  // padded LDS pitch in bf16 elems

static __device__ __forceinline__ unsigned short f2bf(float f) {
  union { float f; unsigned u; } c; c.f = f;
  unsigned u = c.u;
  return (unsigned short)((u + 0x7fffu + ((u >> 16) & 1u)) >> 16);  // RNE
}
static __device__ __forceinline__ float bf2f(unsigned short b) {
  union { unsigned u; float f; } c; c.u = ((unsigned)b) << 16;
  return c.f;
}

// edge_index may arrive as int64 (reference dtype) or int32 (harness downcast).
static __device__ __forceinline__ int load_idx(const void* ei, int is64, long long pos) {
  if (is64) return (int)((const long long*)ei)[pos];
  return ((const int*)ei)[pos];
}

__global__ __launch_bounds__(64) void k_detect(const void* ei, int nnodes, int* flag) {
  if (threadIdx.x != 0) return;
  const long long* e64 = (const long long*)ei;
  int ok = 1;
  for (int i = 0; i < 64; ++i) {
    long long v = e64[i];
    if (v < 0 || v >= (long long)nnodes) { ok = 0; break; }
  }
  *flag = ok;
}

// K1: h = x @ W (bf16 MFMA, f32 accum), h stored bf16.
// Epilogue also computes ssrc/sdst[n][4] from accumulators (butterfly reduce).
__global__ __launch_bounds__(256) void k_gemm(const float* __restrict__ x,
                                              const float* __restrict__ W,
                                              const float* __restrict__ a,
                                              unsigned short* __restrict__ hbf,
                                              float* __restrict__ ssrc,
                                              float* __restrict__ sdst, int nnodes) {
  __shared__ __align__(16) unsigned short lx[64 * XP];
  __shared__ __align__(16) unsigned short lw[128 * XP];
  const int tid = threadIdx.x;
  const int n0 = blockIdx.x * 64;

  for (int it = 0; it < 8; ++it) {
    int idx = tid + it * 256;
    int r = idx >> 5, i4 = idx & 31;
    int n = n0 + r;
    float4 v = make_float4(0.f, 0.f, 0.f, 0.f);
    if (n < nnodes) v = *(const float4*)(x + (size_t)n * 128 + i4 * 4);
    ushort4_t b; b.x = f2bf(v.x); b.y = f2bf(v.y); b.z = f2bf(v.z); b.w = f2bf(v.w);
    *(ushort4_t*)&lx[r * XP + i4 * 4] = b;
  }
  for (int it = 0; it < 64; ++it) {
    int idx = tid + it * 256;
    int hh = idx >> 12, i = (idx >> 5) & 127, o = idx & 31;
    int col = hh * 32 + o;
    lw[col * XP + i] = f2bf(W[idx]);
  }
  __syncthreads();

  const int wave = tid >> 6, lane = tid & 63;
  const int m0 = wave * 16;
  const int lr = lane & 15, lh = lane >> 4;

  f32x4 acc[8] = {};
  for (int kk = 0; kk < 4; ++kk) {
    short8 av = *(const short8*)&lx[(m0 + lr) * XP + kk * 32 + lh * 8];
#pragma unroll
    for (int f = 0; f < 8; ++f) {
      short8 bv = *(const short8*)&lw[(f * 16 + lr) * XP + kk * 32 + lh * 8];
      acc[f] = __builtin_amdgcn_mfma_f32_16x16x32_bf16(av, bv, acc[f], 0, 0, 0);
    }
  }

  // a coefficients for this lane's lr: av4[hh] = {src_lo, src_hi, dst_lo, dst_hi}
  float avc[4][4];
#pragma unroll
  for (int hh = 0; hh < 4; ++hh) {
    avc[hh][0] = a[hh * 64 + lr];
    avc[hh][1] = a[hh * 64 + 16 + lr];
    avc[hh][2] = a[hh * 64 + 32 + lr];
    avc[hh][3] = a[hh * 64 + 48 + lr];
  }

#pragma unroll
  for (int j = 0; j < 4; ++j) {
    int n = n0 + m0 + lh * 4 + j;
    // store h row as bf16 (cols f*16+lr)
#pragma unroll
    for (int f = 0; f < 8; ++f) {
      if (n < nnodes) hbf[(size_t)n * 128 + f * 16 + lr] = f2bf(acc[f][j]);
    }
    // attention scalars: reduce over lr within 16-lane group
#pragma unroll
    for (int hh = 0; hh < 4; ++hh) {
      float s0 = acc[2 * hh][j] * avc[hh][0] + acc[2 * hh + 1][j] * avc[hh][1];
      float s1 = acc[2 * hh][j] * avc[hh][2] + acc[2 * hh + 1][j] * avc[hh][3];
#pragma unroll
      for (int m = 1; m < 16; m <<= 1) {
        s0 += __shfl_xor(s0, m);
        s1 += __shfl_xor(s1, m);
      }
      if (lr == hh && n < nnodes) {
        ssrc[(size_t)n * 4 + hh] = s0;
        sdst[(size_t)n * 4 + hh] = s1;
      }
    }
  }
}

// ---- CSR build ----
__global__ __launch_bounds__(256) void k_deg(const void* __restrict__ ei, const int* __restrict__ flag,
                                             int* __restrict__ deg, int E) {
  int e = blockIdx.x * 256 + threadIdx.x;
  if (e >= E) return;
  int dst = load_idx(ei, *flag, (long long)E + e);
  atomicAdd(&deg[dst], 1);
}

__global__ __launch_bounds__(256) void k_scan1(const int* __restrict__ deg, int* __restrict__ rowstart,
                                               int* __restrict__ bsum, int N) {
  __shared__ int l[256];
  int t = threadIdx.x;
  int gid = blockIdx.x * 256 + t;
  int v = (gid < N) ? deg[gid] : 0;
  l[t] = v;
  __syncthreads();
  for (int off = 1; off < 256; off <<= 1) {
    int u = (t >= off) ? l[t - off] : 0;
    __syncthreads();
    l[t] += u;
    __syncthreads();
  }
  if (gid < N) rowstart[gid] = l[t] - v;
  if (t == 255) bsum[blockIdx.x] = l[255];
}

__global__ __launch_bounds__(512) void k_scan2(int* __restrict__ bsum, int nb) {
  __shared__ int l[512];
  int t = threadIdx.x;
  int v = (t < nb) ? bsum[t] : 0;
  l[t] = v;
  __syncthreads();
  for (int off = 1; off < 512; off <<= 1) {
    int u = (t >= off) ? l[t - off] : 0;
    __syncthreads();
    l[t] += u;
    __syncthreads();
  }
  if (t < nb) bsum[t] = l[t] - v;
}

__global__ __launch_bounds__(256) void k_scan3(int* __restrict__ rowstart, const int* __restrict__ bsum,
                                               int* __restrict__ cursor, int N) {
  int gid = blockIdx.x * 256 + threadIdx.x;
  if (gid < N) {
    int r = rowstart[gid] + bsum[blockIdx.x];
    rowstart[gid] = r;
    cursor[gid] = r;
  }
}

__global__ __launch_bounds__(256) void k_scatter(const void* __restrict__ ei, const int* __restrict__ flag,
                                                 int* __restrict__ cursor, int* __restrict__ eidx, int E) {
  int e = blockIdx.x * 256 + threadIdx.x;
  if (e >= E) return;
  int is64 = *flag;
  int src = load_idx(ei, is64, e);
  int dst = load_idx(ei, is64, (long long)E + e);
  int pos = atomicAdd(&cursor[dst], 1);
  eidx[pos] = src;
}

// ---- gather: one wave per dst; bf16 h, 1 dword/lane/edge; fused softmax ----
__global__ __launch_bounds__(256) void k_gather(const unsigned short* __restrict__ hbf,
                                                const float* __restrict__ ssrc,
                                                const float* __restrict__ sdst,
                                                const int* __restrict__ rowstart,
                                                const int* __restrict__ deg,
                                                const int* __restrict__ eidx,
                                                float* __restrict__ out, int N) {
  int wid = (blockIdx.x * 256 + threadIdx.x) >> 6;
  int lane = threadIdx.x & 63;
  if (wid >= N) return;
  const int dst = wid;
  const int beg = rowstart[dst];
  const int end = beg + deg[dst];
  const int hh = lane >> 4;                 // head of cols {2*lane, 2*lane+1}
  const float sd = sdst[(size_t)dst * 4 + hh];
  float acc0 = 0.f, acc1 = 0.f, ps = 0.f;

  int i = beg;
  for (; i + 1 < end; i += 2) {
    int sA = eidx[i], sB = eidx[i + 1];
    unsigned hvA = *(const unsigned*)(hbf + (size_t)sA * 128 + lane * 2);
    unsigned hvB = *(const unsigned*)(hbf + (size_t)sB * 128 + lane * 2);
    float eA = ssrc[(size_t)sA * 4 + hh] + sd;
    float eB = ssrc[(size_t)sB * 4 + hh] + sd;
    eA = eA > 0.f ? eA : 0.2f * eA;
    eB = eB > 0.f ? eB : 0.2f * eB;
    float pA = __expf(eA), pB = __expf(eB);
    acc0 += pA * bf2f((unsigned short)(hvA & 0xffff));
    acc1 += pA * bf2f((unsigned short)(hvA >> 16));
    acc0 += pB * bf2f((unsigned short)(hvB & 0xffff));
    acc1 += pB * bf2f((unsigned short)(hvB >> 16));
    ps += pA + pB;
  }
  if (i < end) {
    int sA = eidx[i];
    unsigned hvA = *(const unsigned*)(hbf + (size_t)sA * 128 + lane * 2);
    float eA = ssrc[(size_t)sA * 4 + hh] + sd;
    eA = eA > 0.f ? eA : 0.2f * eA;
    float pA = __expf(eA);
    acc0 += pA * bf2f((unsigned short)(hvA & 0xffff));
    acc1 += pA * bf2f((unsigned short)(hvA >> 16));
    ps += pA;
  }
  float r = (ps > 0.f) ? 1.f / ps : 0.f;
  float2 o = make_float2(acc0 * r, acc1 * r);
  __builtin_nontemporal_store(o.x, out + (size_t)dst * 128 + lane * 2);
  __builtin_nontemporal_store(o.y, out + (size_t)dst * 128 + lane * 2 + 1);
}

extern "C" void kernel_launch(void* const* d_in, const int* in_sizes, int n_in,
                              void* d_out, int out_size, void* d_ws, size_t ws_size,
                              hipStream_t stream) {
  const float* x = (const float*)d_in[0];
  const void*  ei = d_in[1];
  const float* W = (const float*)d_in[2];
  const float* a = (const float*)d_in[3];
  float* out = (float*)d_out;

  const int N = in_sizes[0] / 128;
  const int E = in_sizes[1] / 2;
  const int NB = (N + 255) / 256;              // scan blocks (<=512)

  char* ws = (char*)d_ws;
  unsigned short* hbf = (unsigned short*)ws;             ws += (size_t)N * 128 * 2;
  float* ssrc     = (float*)ws;                          ws += (size_t)N * 4 * 4;
  float* sdst     = (float*)ws;                          ws += (size_t)N * 4 * 4;
  int*   deg      = (int*)ws;                            ws += (size_t)N * 4;
  int*   rowstart = (int*)ws;                            ws += (size_t)N * 4;
  int*   cursor   = (int*)ws;                            ws += (size_t)N * 4;
  int*   bsum     = (int*)ws;                            ws += 512 * 4;
  int*   eidx     = (int*)ws;                            ws += (size_t)E * 4;
  int*   flag     = (int*)ws;

  hipMemsetAsync(deg, 0, (size_t)N * 4, stream);

  k_detect<<<1, 64, 0, stream>>>(ei, N, flag);
  k_gemm<<<(N + 63) / 64, 256, 0, stream>>>(x, W, a, hbf, ssrc, sdst, N);
  k_deg<<<(E + 255) / 256, 256, 0, stream>>>(ei, flag, deg, E);
  k_scan1<<<NB, 256, 0, stream>>>(deg, rowstart, bsum, N);
  k_scan2<<<1, 512, 0, stream>>>(bsum, NB);
  k_scan3<<<NB, 256, 0, stream>>>(rowstart, bsum, cursor, N);
  k_scatter<<<(E + 255) / 256, 256, 0, stream>>>(ei, flag, cursor, eidx, E);
  k_gather<<<(N + 3) / 4, 256, 0, stream>>>(hbf, ssrc, sdst, rowstart, deg, eidx, out, N);
}

// Round 4
// 274.806 us; speedup vs baseline: 11.2945x; 1.2490x over previous
//
#include <hip/hip_runtime.h>

using f32x4  = __attribute__((ext_vector_type(4))) float;
using short8 = __attribute__((ext_vector_type(8))) short;
using ushort4_t = __attribute__((ext_vector_type(4))) unsigned short;

#define XP 136  // padded LDS pitch in bf16 elems

static __device__ __forceinline__ unsigned short f2bf(float f) {
  union { float f; unsigned u; } c; c.f = f;
  unsigned u = c.u;
  return (unsigned short)((u + 0x7fffu + ((u >> 16) & 1u)) >> 16);  // RNE
}
static __device__ __forceinline__ float bf2f(unsigned short b) {
  union { unsigned u; float f; } c; c.u = ((unsigned)b) << 16;
  return c.f;
}

// edge_index may arrive as int64 (reference dtype) or int32 (harness downcast).
static __device__ __forceinline__ int load_idx(const void* ei, int is64, long long pos) {
  if (is64) return (int)((const long long*)ei)[pos];
  return ((const int*)ei)[pos];
}

__global__ __launch_bounds__(64) void k_detect(const void* ei, int nnodes, int* flag) {
  if (threadIdx.x != 0) return;
  const long long* e64 = (const long long*)ei;
  int ok = 1;
  for (int i = 0; i < 64; ++i) {
    long long v = e64[i];
    if (v < 0 || v >= (long long)nnodes) { ok = 0; break; }
  }
  *flag = ok;
}

// K1: h = x @ W (bf16 MFMA, f32 accum), h stored bf16.
// Epilogue computes ssrc/sdst[n][4] from accumulators (butterfly reduce).
__global__ __launch_bounds__(256) void k_gemm(const float* __restrict__ x,
                                              const float* __restrict__ W,
                                              const float* __restrict__ a,
                                              unsigned short* __restrict__ hbf,
                                              float* __restrict__ ssrc,
                                              float* __restrict__ sdst, int nnodes) {
  __shared__ __align__(16) unsigned short lx[64 * XP];
  __shared__ __align__(16) unsigned short lw[128 * XP];
  const int tid = threadIdx.x;
  const int n0 = blockIdx.x * 64;

  for (int it = 0; it < 8; ++it) {
    int idx = tid + it * 256;
    int r = idx >> 5, i4 = idx & 31;
    int n = n0 + r;
    float4 v = make_float4(0.f, 0.f, 0.f, 0.f);
    if (n < nnodes) v = *(const float4*)(x + (size_t)n * 128 + i4 * 4);
    ushort4_t b; b.x = f2bf(v.x); b.y = f2bf(v.y); b.z = f2bf(v.z); b.w = f2bf(v.w);
    *(ushort4_t*)&lx[r * XP + i4 * 4] = b;
  }
  for (int it = 0; it < 64; ++it) {
    int idx = tid + it * 256;
    int hh = idx >> 12, i = (idx >> 5) & 127, o = idx & 31;
    int col = hh * 32 + o;
    lw[col * XP + i] = f2bf(W[idx]);
  }
  __syncthreads();

  const int wave = tid >> 6, lane = tid & 63;
  const int m0 = wave * 16;
  const int lr = lane & 15, lh = lane >> 4;

  f32x4 acc[8] = {};
  for (int kk = 0; kk < 4; ++kk) {
    short8 av = *(const short8*)&lx[(m0 + lr) * XP + kk * 32 + lh * 8];
#pragma unroll
    for (int f = 0; f < 8; ++f) {
      short8 bv = *(const short8*)&lw[(f * 16 + lr) * XP + kk * 32 + lh * 8];
      acc[f] = __builtin_amdgcn_mfma_f32_16x16x32_bf16(av, bv, acc[f], 0, 0, 0);
    }
  }

  float avc[4][4];
#pragma unroll
  for (int hh = 0; hh < 4; ++hh) {
    avc[hh][0] = a[hh * 64 + lr];
    avc[hh][1] = a[hh * 64 + 16 + lr];
    avc[hh][2] = a[hh * 64 + 32 + lr];
    avc[hh][3] = a[hh * 64 + 48 + lr];
  }

#pragma unroll
  for (int j = 0; j < 4; ++j) {
    int n = n0 + m0 + lh * 4 + j;
#pragma unroll
    for (int f = 0; f < 8; ++f) {
      if (n < nnodes) hbf[(size_t)n * 128 + f * 16 + lr] = f2bf(acc[f][j]);
    }
#pragma unroll
    for (int hh = 0; hh < 4; ++hh) {
      float s0 = acc[2 * hh][j] * avc[hh][0] + acc[2 * hh + 1][j] * avc[hh][1];
      float s1 = acc[2 * hh][j] * avc[hh][2] + acc[2 * hh + 1][j] * avc[hh][3];
#pragma unroll
      for (int m = 1; m < 16; m <<= 1) {
        s0 += __shfl_xor(s0, m);
        s1 += __shfl_xor(s1, m);
      }
      if (lr == hh && n < nnodes) {
        ssrc[(size_t)n * 4 + hh] = s0;
        sdst[(size_t)n * 4 + hh] = s1;
      }
    }
  }
}

// ---- CSR build ----
// prep: downcast edge index to int32 (src32/dst32 live in d_out scratch) + degree histogram
__global__ __launch_bounds__(256) void k_prep(const void* __restrict__ ei, const int* __restrict__ flag,
                                              int* __restrict__ src32, int* __restrict__ dst32,
                                              int* __restrict__ deg, int E) {
  int e = blockIdx.x * 256 + threadIdx.x;
  if (e >= E) return;
  int is64 = *flag;
  int s = load_idx(ei, is64, e);
  int d = load_idx(ei, is64, (long long)E + e);
  src32[e] = s;
  dst32[e] = d;
  atomicAdd(&deg[d], 1);
}

__global__ __launch_bounds__(256) void k_scan1(const int* __restrict__ deg, int* __restrict__ rowstart,
                                               int* __restrict__ bsum, int N) {
  __shared__ int l[256];
  int t = threadIdx.x;
  int gid = blockIdx.x * 256 + t;
  int v = (gid < N) ? deg[gid] : 0;
  l[t] = v;
  __syncthreads();
  for (int off = 1; off < 256; off <<= 1) {
    int u = (t >= off) ? l[t - off] : 0;
    __syncthreads();
    l[t] += u;
    __syncthreads();
  }
  if (gid < N) rowstart[gid] = l[t] - v;
  if (t == 255) bsum[blockIdx.x] = l[255];
}

__global__ __launch_bounds__(512) void k_scan2(int* __restrict__ bsum, int nb) {
  __shared__ int l[512];
  int t = threadIdx.x;
  int v = (t < nb) ? bsum[t] : 0;
  l[t] = v;
  __syncthreads();
  for (int off = 1; off < 512; off <<= 1) {
    int u = (t >= off) ? l[t - off] : 0;
    __syncthreads();
    l[t] += u;
    __syncthreads();
  }
  if (t < nb) bsum[t] = l[t] - v;
}

__global__ __launch_bounds__(256) void k_scan3(int* __restrict__ rowstart, const int* __restrict__ bsum,
                                               int* __restrict__ cursor, int N) {
  int gid = blockIdx.x * 256 + threadIdx.x;
  if (gid < N) {
    int r = rowstart[gid] + bsum[blockIdx.x];
    rowstart[gid] = r;
    cursor[gid] = r;
  }
}

// Partitioned scatter: partition p = blockIdx%8 handles dst range [p*N/8,(p+1)*N/8).
// With round-robin block->XCD mapping each L2's hot write window is ~0.8 MB ->
// eidx lines collect all their writes before writeback (kills 16x amplification).
// Correctness does NOT depend on the mapping.
__global__ __launch_bounds__(256) void k_scatter(const int* __restrict__ src32,
                                                 const int* __restrict__ dst32,
                                                 int* __restrict__ cursor,
                                                 int* __restrict__ eidx, int E, int N) {
  const int part = blockIdx.x & 7;
  const int wblk = blockIdx.x >> 3;
  const int nwb = gridDim.x >> 3;
  const int lo = (int)(((long long)N * part) >> 3);
  const int hi = (int)(((long long)N * (part + 1)) >> 3);
  for (int e = wblk * 256 + threadIdx.x; e < E; e += nwb * 256) {
    int d = dst32[e];
    if (d >= lo && d < hi) {
      int s = src32[e];
      int pos = atomicAdd(&cursor[d], 1);
      eidx[pos] = s;
    }
  }
}

// ---- gather: one wave per dst; bf16 h; 4-deep software pipeline ----
__global__ __launch_bounds__(256) void k_gather(const unsigned short* __restrict__ hbf,
                                                const float* __restrict__ ssrc,
                                                const float* __restrict__ sdst,
                                                const int* __restrict__ rowstart,
                                                const int* __restrict__ deg,
                                                const int* __restrict__ eidx,
                                                float* __restrict__ out, int N) {
  int wid = (blockIdx.x * 256 + threadIdx.x) >> 6;
  int lane = threadIdx.x & 63;
  if (wid >= N) return;
  const int dst = wid;
  const int beg = rowstart[dst];
  const int end = beg + deg[dst];
  const int hh = lane >> 4;                 // head of cols {2*lane, 2*lane+1}
  const float sd = sdst[(size_t)dst * 4 + hh];
  float acc0 = 0.f, acc1 = 0.f, ps = 0.f;

  int i = beg;
  for (; i + 3 < end; i += 4) {
    int sA = eidx[i], sB = eidx[i + 1], sC = eidx[i + 2], sD = eidx[i + 3];
    unsigned hvA = *(const unsigned*)(hbf + (size_t)sA * 128 + lane * 2);
    unsigned hvB = *(const unsigned*)(hbf + (size_t)sB * 128 + lane * 2);
    unsigned hvC = *(const unsigned*)(hbf + (size_t)sC * 128 + lane * 2);
    unsigned hvD = *(const unsigned*)(hbf + (size_t)sD * 128 + lane * 2);
    float eA = ssrc[(size_t)sA * 4 + hh] + sd;
    float eB = ssrc[(size_t)sB * 4 + hh] + sd;
    float eC = ssrc[(size_t)sC * 4 + hh] + sd;
    float eD = ssrc[(size_t)sD * 4 + hh] + sd;
    eA = eA > 0.f ? eA : 0.2f * eA;
    eB = eB > 0.f ? eB : 0.2f * eB;
    eC = eC > 0.f ? eC : 0.2f * eC;
    eD = eD > 0.f ? eD : 0.2f * eD;
    float pA = __expf(eA), pB = __expf(eB), pC = __expf(eC), pD = __expf(eD);
    acc0 += pA * bf2f((unsigned short)(hvA & 0xffff));
    acc1 += pA * bf2f((unsigned short)(hvA >> 16));
    acc0 += pB * bf2f((unsigned short)(hvB & 0xffff));
    acc1 += pB * bf2f((unsigned short)(hvB >> 16));
    acc0 += pC * bf2f((unsigned short)(hvC & 0xffff));
    acc1 += pC * bf2f((unsigned short)(hvC >> 16));
    acc0 += pD * bf2f((unsigned short)(hvD & 0xffff));
    acc1 += pD * bf2f((unsigned short)(hvD >> 16));
    ps += (pA + pB) + (pC + pD);
  }
  for (; i < end; ++i) {
    int sA = eidx[i];
    unsigned hvA = *(const unsigned*)(hbf + (size_t)sA * 128 + lane * 2);
    float eA = ssrc[(size_t)sA * 4 + hh] + sd;
    eA = eA > 0.f ? eA : 0.2f * eA;
    float pA = __expf(eA);
    acc0 += pA * bf2f((unsigned short)(hvA & 0xffff));
    acc1 += pA * bf2f((unsigned short)(hvA >> 16));
    ps += pA;
  }
  float r = (ps > 0.f) ? 1.f / ps : 0.f;
  __builtin_nontemporal_store(acc0 * r, out + (size_t)dst * 128 + lane * 2);
  __builtin_nontemporal_store(acc1 * r, out + (size_t)dst * 128 + lane * 2 + 1);
}

extern "C" void kernel_launch(void* const* d_in, const int* in_sizes, int n_in,
                              void* d_out, int out_size, void* d_ws, size_t ws_size,
                              hipStream_t stream) {
  const float* x = (const float*)d_in[0];
  const void*  ei = d_in[1];
  const float* W = (const float*)d_in[2];
  const float* a = (const float*)d_in[3];
  float* out = (float*)d_out;

  const int N = in_sizes[0] / 128;
  const int E = in_sizes[1] / 2;
  const int NB = (N + 255) / 256;              // scan blocks (<=512)

  char* ws = (char*)d_ws;
  unsigned short* hbf = (unsigned short*)ws;             ws += (size_t)N * 128 * 2;
  float* ssrc     = (float*)ws;                          ws += (size_t)N * 4 * 4;
  float* sdst     = (float*)ws;                          ws += (size_t)N * 4 * 4;
  int*   deg      = (int*)ws;                            ws += (size_t)N * 4;
  int*   rowstart = (int*)ws;                            ws += (size_t)N * 4;
  int*   cursor   = (int*)ws;                            ws += (size_t)N * 4;
  int*   bsum     = (int*)ws;                            ws += 512 * 4;
  int*   eidx     = (int*)ws;                            ws += (size_t)E * 4;
  int*   flag     = (int*)ws;

  // src32/dst32 scratch aliased into d_out (12.8 MB << 51.2 MB); fully
  // overwritten by k_gather afterwards, so no state leaks across calls.
  int* src32 = (int*)d_out;
  int* dst32 = src32 + E;

  hipMemsetAsync(deg, 0, (size_t)N * 4, stream);

  k_detect<<<1, 64, 0, stream>>>(ei, N, flag);
  k_gemm<<<(N + 63) / 64, 256, 0, stream>>>(x, W, a, hbf, ssrc, sdst, N);
  k_prep<<<(E + 255) / 256, 256, 0, stream>>>(ei, flag, src32, dst32, deg, E);
  k_scan1<<<NB, 256, 0, stream>>>(deg, rowstart, bsum, N);
  k_scan2<<<1, 512, 0, stream>>>(bsum, NB);
  k_scan3<<<NB, 256, 0, stream>>>(rowstart, bsum, cursor, N);
  k_scatter<<<2048, 256, 0, stream>>>(src32, dst32, cursor, eidx, E, N);
  k_gather<<<(N + 3) / 4, 256, 0, stream>>>(hbf, ssrc, sdst, rowstart, deg, eidx, out, N);
}